// Round 13
// baseline (195.172 us; speedup 1.0000x reference)
//
#include <hip/hip_runtime.h>
#include <hip/hip_bf16.h>
#include <stdint.h>

// Problem constants (B=2, N=2048, C=1024, H=16, D=64)
#define SL_F 0.18033688011112043f   // SCALE * log2(e): softmax in exp2 domain

typedef unsigned short u16;
typedef unsigned int u32;
typedef __attribute__((ext_vector_type(8))) short bf16x8;   // 8 bf16 = 4 VGPRs
typedef __attribute__((ext_vector_type(4))) float f32x4;

__device__ __forceinline__ u16 f2bf(float f) {
    union { float f; u32 u; } v; v.f = f;
    return (u16)((v.u + 0x7fffu + ((v.u >> 16) & 1u)) >> 16);  // RNE
}
__device__ __forceinline__ u32 pack2bf(float a, float b) {
    union { __hip_bfloat162 h; u32 u; } p;
    p.h = __float22bfloat162_rn(make_float2(a, b));
    return p.u;
}

// async global->LDS, 16B per lane; LDS dest = wave-uniform base + lane*16.
// Global src is PER-LANE: coalescing needs the 64-address SET contiguous,
// not lane-identity order (r11 verified: permuted-slot chunks).
__device__ __forceinline__ void gl_lds16(const u16* g, u16* l) {
    __builtin_amdgcn_global_load_lds(
        (const __attribute__((address_space(1))) u32*)g,
        (__attribute__((address_space(3))) u32*)l, 16, 0, 0);
}

// ---------------- fp32 -> bf16 TILED conversion of x, w_qkv, w_proj ---------
// Fragment-tiled layout (r9, VERIFIED): chunk(g,kb)=1KB, slot order =
// gl_lds16 deposit. Staging = chunk + lane*16 (8 full 128B lines/instr).
__global__ __launch_bounds__(256) void convert_k(
    const float* __restrict__ x, const float* __restrict__ w1,
    const float* __restrict__ w2,
    u16* __restrict__ xb, u16* __restrict__ w1b, u16* __restrict__ w2b)
{
    const int t = blockIdx.x * 256 + threadIdx.x;   // global slot id
    const int XA = 524288, XW1 = 393216;            // slots: 4096*128, 3072*128
    const float* src; u16* dst; int s;
    if (t < XA)            { src = x;  dst = xb;  s = t; }
    else if (t < XA + XW1) { src = w1; dst = w1b; s = t - XA; }
    else                   { src = w2; dst = w2b; s = t - XA - XW1; }
    const int c = s >> 6;                    // chunk (wave-uniform)
    const int u = s & 63;
    const int l = (u >> 2) + 16 * (u & 3);   // slot within chunk
    const int g = c >> 5, kb = c & 31;
    const int row = g * 16 + (l & 15);
    const int k0 = kb * 32 + (l >> 4) * 8;
    const float4 v0 = *(const float4*)&src[(size_t)row * 1024 + k0];
    const float4 v1 = *(const float4*)&src[(size_t)row * 1024 + k0 + 4];
    uint4 o;
    o.x = pack2bf(v0.x, v0.y); o.y = pack2bf(v0.z, v0.w);
    o.z = pack2bf(v1.x, v1.y); o.w = pack2bf(v1.z, v1.w);
    *(uint4*)&dst[((size_t)c * 64 + l) * 8] = o;
}

// ---------------- QKV GEMM: out[m,n] = sum_k A[m,k]*W[n,k] + bias ------------
// r6 proven body + 24x32 grid + r9 tiled A/B staging + r11 row-major-interior
// K/V^T chunks + r12 pre-scaled Q (all verified).
__global__ __launch_bounds__(256) void qkv_gemm(
    const u16* __restrict__ A, const u16* __restrict__ Bw,
    const float* __restrict__ bias,
    u16* __restrict__ Qb, u16* __restrict__ Kb, u16* __restrict__ VTb)
{
    __shared__ __align__(16) u16 Al[2][8 * 512];
    __shared__ __align__(16) u16 Bl[2][8 * 512];
    const int tid = threadIdx.x;
    const int lane = tid & 63;
    const int w = tid >> 6;
    const int la = lane & 15, qd = lane >> 4;
    const int m0 = blockIdx.y * 128;
    const int n0 = blockIdx.x * 128;
    const int wm = (w >> 1) * 64, wn = (w & 1) * 64;

    const u16* Ag0 = A + ((size_t)((m0 >> 4) + 2 * w) * 32) * 512 + lane * 8;
    const u16* Ag1 = Ag0 + 32 * 512;
    const u16* Bg0 = Bw + ((size_t)((n0 >> 4) + 2 * w) * 32) * 512 + lane * 8;
    const u16* Bg1 = Bg0 + 32 * 512;

    auto stage = [&](int k0, int b) {
        const size_t ko = (size_t)(k0 >> 5) * 512;
        gl_lds16(Ag0 + ko, &Al[b][(2 * w) * 512]);
        gl_lds16(Ag1 + ko, &Al[b][(2 * w + 1) * 512]);
        gl_lds16(Bg0 + ko, &Bl[b][(2 * w) * 512]);
        gl_lds16(Bg1 + ko, &Bl[b][(2 * w + 1) * 512]);
    };

    f32x4 acc[4][4] = {};
    int buf = 0;
    stage(0, 0);

    for (int k0 = 0; k0 < 1024; k0 += 32) {
        __syncthreads();                       // drains prev prefetch (vmcnt 0)
        if (k0 + 32 < 1024) stage(k0 + 32, buf ^ 1);

        bf16x8 af[4], bfr[4];
#pragma unroll
        for (int i = 0; i < 4; i++)
            af[i] = *(const bf16x8*)&Al[buf][(((unsigned)wm >> 4) + i) * 512 + lane * 8];
#pragma unroll
        for (int j = 0; j < 4; j++)
            bfr[j] = *(const bf16x8*)&Bl[buf][(((unsigned)wn >> 4) + j) * 512 + lane * 8];
#pragma unroll
        for (int i = 0; i < 4; i++)
#pragma unroll
            for (int j = 0; j < 4; j++)
                acc[i][j] = __builtin_amdgcn_mfma_f32_16x16x32_bf16(
                    af[i], bfr[j], acc[i][j], 0, 0, 0);
        buf ^= 1;
    }

    // Epilogue. C/D: col = lane&15 (-> d), row = qd*4 + reg (-> n).
    const int b_ = m0 >> 11;                         // batch (block-uniform)
    const int nb = (m0 & 2047) + wm;                 // token base (64-aligned)
#pragma unroll
    for (int j = 0; j < 4; j++) {
        const int colb = n0 + wn + j * 16;           // wave-uniform
        const int col = colb + la;
        const float bv = bias[col];
        const int t = colb >> 10;                    // wave-uniform selector
        const int hd = col & 1023, h = hd >> 6, d = hd & 63;
        const int bh = b_ * 16 + h;
        if (t == 0) {
            u16* QB = Qb + ((size_t)bh * 2048 + nb) * 64 + d;
#pragma unroll
            for (int i = 0; i < 4; i++)
#pragma unroll
                for (int r = 0; r < 4; r++)
                    QB[(i * 16 + qd * 4 + r) * 64] =
                        f2bf((acc[i][j][r] + bv) * SL_F);   // pre-scaled Q
        } else if (t == 1) {
            u16* KB = Kb + (size_t)bh * 131072
                    + (size_t)((nb >> 4) * 2 + (d >> 5)) * 512 + (d & 31);
#pragma unroll
            for (int i = 0; i < 4; i++)
#pragma unroll
                for (int r = 0; r < 4; r++)
                    KB[i * 1024 + (qd * 4 + r) * 32] = f2bf(acc[i][j][r] + bv);
        } else {
            u16* VB = VTb + (size_t)bh * 131072
                    + (size_t)(d >> 4) * 32768 + (d & 15) * 32;
#pragma unroll
            for (int i = 0; i < 4; i++)
#pragma unroll
                for (int r = 0; r < 4; r++)
                    VB[((nb >> 5) + (i >> 1)) * 512 + (i & 1) * 16 + qd * 4 + r]
                        = f2bf(acc[i][j][r] + bv);
        }
    }
}

// ---------------- proj GEMM, BK=64; A and B both from tiled layouts ----------
// (r10/r11, verified; unchanged)
__global__ __launch_bounds__(256) void proj_gemm(
    const u16* __restrict__ A, const u16* __restrict__ Bw,
    const float* __restrict__ bias, float* __restrict__ Out)
{
    __shared__ __align__(16) u16 Al[2][16 * 512];   // 32 KB
    __shared__ __align__(16) u16 Bl[2][8 * 512];    // 16 KB
    const int tid = threadIdx.x;
    const int lane = tid & 63;
    const int w = tid >> 6;
    const int la = lane & 15, qd = lane >> 4;
    const int K = 1024;
    const int m0 = blockIdx.y * 128;
    const int n0 = blockIdx.x * 64;
    const int wm = (w >> 1) * 64, wn = (w & 1) * 32;

    const u16* Ab[4];
#pragma unroll
    for (int t = 0; t < 4; t++) {
        const int ck = 4 * w + t, g = ck >> 1, h = ck & 1;
        Ab[t] = A + (((size_t)(m0 >> 4) + g) * 32 + h) * 512 + lane * 8;
    }
    const u16* Bg = Bw + ((size_t)((n0 >> 4) + w) * 32) * 512 + lane * 8;

    auto stage = [&](int k0, int b) {
#pragma unroll
        for (int t = 0; t < 4; t++)
            gl_lds16(Ab[t] + (size_t)(k0 >> 5) * 512, &Al[b][(4 * w + t) * 512]);
#pragma unroll
        for (int t = 0; t < 2; t++)
            gl_lds16(Bg + (size_t)((k0 >> 5) + t) * 512, &Bl[b][(2 * w + t) * 512]);
    };

    f32x4 acc[4][2] = {};
    int buf = 0;
    stage(0, 0);

    for (int k0 = 0; k0 < K; k0 += 64) {
        __syncthreads();                       // drains prev prefetch (vmcnt 0)
        if (k0 + 64 < K) stage(k0 + 64, buf ^ 1);

        bf16x8 af[4][2], bfr[2][2];
#pragma unroll
        for (int i = 0; i < 4; i++) {
            const int g = ((unsigned)wm >> 4) + i;
#pragma unroll
            for (int h = 0; h < 2; h++)
                af[i][h] = *(const bf16x8*)&Al[buf][(g * 2 + h) * 512 + lane * 8];
        }
#pragma unroll
        for (int j = 0; j < 2; j++) {
            const int g = ((unsigned)wn >> 4) + j;
#pragma unroll
            for (int h = 0; h < 2; h++)
                bfr[j][h] = *(const bf16x8*)&Bl[buf][(g * 2 + h) * 512 + lane * 8];
        }
#pragma unroll
        for (int i = 0; i < 4; i++)
#pragma unroll
            for (int j = 0; j < 2; j++) {
                f32x4 c = acc[i][j];
                c = __builtin_amdgcn_mfma_f32_16x16x32_bf16(af[i][0], bfr[j][0], c, 0, 0, 0);
                c = __builtin_amdgcn_mfma_f32_16x16x32_bf16(af[i][1], bfr[j][1], c, 0, 0, 0);
                acc[i][j] = c;
            }
        buf ^= 1;
    }

    // Epilogue (fp32 out + bias). C/D layout: col = lane&15, row = qd*4 + r.
#pragma unroll
    for (int j = 0; j < 2; j++) {
        const int col = n0 + wn + j * 16 + la;
        const float bv = bias[col];
#pragma unroll
        for (int i = 0; i < 4; i++)
#pragma unroll
            for (int r = 0; r < 4; r++) {
                const int row = m0 + wm + i * 16 + qd * 4 + r;
                Out[(size_t)row * 1024 + col] = acc[i][j][r] + bv;
            }
    }
}

// ---------------- causal flash attention, 4 waves x 32 q-rows ----------------
// r13: r12's staged-BW halving gained only 2us (42.2us; 3.3 TB/s << ceiling)
// -> attn is NOT staging-bound. Dominant fixed term: LDS reads — every wave
// reads the whole K,V tile per iter (36 b128 serving 32 MFMA); total 1.25 GB
// ~ 15us floor at 85 B/cyc/CU. Fix: 32 q-rows/wave (2 Q-groups A,B): K/V
// fragments reused across both groups -> 40 reads serve 64 MFMA; wave-iters
// halve (34816 -> 17408); total LDS reads ~0.7 GB. Block = 4 waves x 32 rows
// = 128 q-rows; pairs {T,15-T} -> uniform 17 iters; grid 256 (bh low bits).
// LDS 84KB -> 1 block/CU, 4 waves/CU; ILP within the doubled wave covers
// latency (32 indep MFMA, 64 indep exp2). Q pre-scaled; K/V tiled chunks +
// permuted-lane staging (r11); Ob proj-A-tiled (r10).
__global__ __launch_bounds__(256, 1) void attn_k(
    const u16* __restrict__ Qb, const u16* __restrict__ Kb,
    const u16* __restrict__ VTb, u16* __restrict__ Ob)
{
    __shared__ __align__(16) u16 Kl[2][16 * 512];   // 32 KB: chunk ck=c*2+h
    __shared__ __align__(16) u16 Vl[2][16 * 512];   // 32 KB: chunk cv=c2*4+kc
    __shared__ __align__(16) u16 Pl[4][2][16 * 72]; // per-wave, per-group P
    const int bh = blockIdx.x & 31;
    const int pairT = blockIdx.x >> 5;              // 0..7
    const int tid = threadIdx.x;
    const int lane = tid & 63;
    const int w = tid >> 6;                         // 0..3
    const int la = lane & 15, qd = lane >> 4;

    // permuted in-chunk offset: lane l -> row-major interior (l&15)*32 + (l>>4)*8
    const int perm = (lane & 15) * 32 + (lane >> 4) * 8;
    const u16* Kbh = Kb + (size_t)bh * 131072 + perm;
    const u16* Vbh = VTb + (size_t)bh * 131072 + perm;
    u16* PwA = &Pl[w][0][0];
    u16* PwB = &Pl[w][1][0];

    // stage: wave w stages K chunks 4w..4w+3, V chunks 4w..4w+3 of a j128 tile
    auto stage = [&](int j0, int b) {
#pragma unroll
        for (int t = 0; t < 4; t++) {
            const int ck = 4 * w + t;
            gl_lds16(Kbh + (size_t)((j0 >> 3) + ck) * 512, &Kl[b][ck * 512]);
            gl_lds16(Vbh + (size_t)((ck >> 2) * 64 + (j0 >> 5) + (ck & 3)) * 512,
                     &Vl[b][ck * 512]);
        }
    };

    int buf = 0;
    stage(0, 0);                                    // prologue for first tile

    for (int half = 0; half < 2; half++) {
        const int tile = (half == 0) ? pairT : 15 - pairT;
        const int q0 = tile * 128 + w * 32;
        const int jmax = tile * 128;                // last (diagonal) j128-tile
        const int qrowA = q0 + la;
        const int qrowB = q0 + 16 + la;

        const u16* Qp = Qb + ((size_t)bh * 2048 + q0 + la) * 64 + qd * 8;
        const bf16x8 qfA0 = *(const bf16x8*)Qp;
        const bf16x8 qfA1 = *(const bf16x8*)(Qp + 32);
        const bf16x8 qfB0 = *(const bf16x8*)(Qp + 16 * 64);
        const bf16x8 qfB1 = *(const bf16x8*)(Qp + 16 * 64 + 32);

        f32x4 oA[4] = {}, oB[4] = {};
        float lsumA = 0.f, lsumB = 0.f;

        for (int j0 = 0; j0 <= jmax; j0 += 128) {
            __syncthreads();   // drains prev prefetch (vmcnt 0, all waves)

            const int nj = (j0 + 128 <= jmax) ? (j0 + 128) : ((half == 0) ? 0 : -1);
            if (nj >= 0) stage(nj, buf ^ 1);

            // S^T = K Q'^T for both q-groups; kf shared (the r13 lever)
            f32x4 sA[8], sB[8];
#pragma unroll
            for (int c = 0; c < 8; c++) {
                const bf16x8 kf0 = *(const bf16x8*)&Kl[buf][(c * 2 + 0) * 512 + lane * 8];
                const bf16x8 kf1 = *(const bf16x8*)&Kl[buf][(c * 2 + 1) * 512 + lane * 8];
                f32x4 zA = {}, zB = {};
                zA = __builtin_amdgcn_mfma_f32_16x16x32_bf16(kf0, qfA0, zA, 0, 0, 0);
                zA = __builtin_amdgcn_mfma_f32_16x16x32_bf16(kf1, qfA1, zA, 0, 0, 0);
                zB = __builtin_amdgcn_mfma_f32_16x16x32_bf16(kf0, qfB0, zB, 0, 0, 0);
                zB = __builtin_amdgcn_mfma_f32_16x16x32_bf16(kf1, qfB1, zB, 0, 0, 0);
                sA[c] = zA; sB[c] = zB;
            }

            // p = exp2(s); causal mask only on the diagonal tile
            if (j0 == jmax) {
#pragma unroll
                for (int c = 0; c < 8; c++)
#pragma unroll
                    for (int r = 0; r < 4; r++) {
                        const int j = j0 + c * 16 + qd * 4 + r;
                        float vA = sA[c][r], vB = sB[c][r];
                        vA = (j > qrowA) ? -1e30f : vA;
                        vB = (j > qrowB) ? -1e30f : vB;
                        sA[c][r] = __builtin_amdgcn_exp2f(vA);
                        sB[c][r] = __builtin_amdgcn_exp2f(vB);
                    }
            } else {
#pragma unroll
                for (int c = 0; c < 8; c++)
#pragma unroll
                    for (int r = 0; r < 4; r++) {
                        sA[c][r] = __builtin_amdgcn_exp2f(sA[c][r]);
                        sB[c][r] = __builtin_amdgcn_exp2f(sB[c][r]);
                    }
            }
#pragma unroll
            for (int c = 0; c < 8; c++)
#pragma unroll
                for (int r = 0; r < 4; r++) {
                    lsumA += sA[c][r];
                    lsumB += sB[c][r];
                }

            // PV in two j-64 halves; vf read ONCE per (c2,half) serves both
            // q-groups (same-wave DS in-order makes P reuse across hh safe)
#pragma unroll
            for (int hh = 0; hh < 2; hh++) {
#pragma unroll
                for (int c = 0; c < 4; c++) {
                    uint2 pwA, pwB;
                    pwA.x = pack2bf(sA[hh * 4 + c][0], sA[hh * 4 + c][1]);
                    pwA.y = pack2bf(sA[hh * 4 + c][2], sA[hh * 4 + c][3]);
                    pwB.x = pack2bf(sB[hh * 4 + c][0], sB[hh * 4 + c][1]);
                    pwB.y = pack2bf(sB[hh * 4 + c][2], sB[hh * 4 + c][3]);
                    *(uint2*)&PwA[la * 72 + c * 16 + qd * 4] = pwA;
                    *(uint2*)&PwB[la * 72 + c * 16 + qd * 4] = pwB;
                }
                const bf16x8 pfA0 = *(const bf16x8*)&PwA[la * 72 + qd * 8];
                const bf16x8 pfA1 = *(const bf16x8*)&PwA[la * 72 + 32 + qd * 8];
                const bf16x8 pfB0 = *(const bf16x8*)&PwB[la * 72 + qd * 8];
                const bf16x8 pfB1 = *(const bf16x8*)&PwB[la * 72 + 32 + qd * 8];
#pragma unroll
                for (int c2 = 0; c2 < 4; c2++) {
                    const bf16x8 vf0 = *(const bf16x8*)&Vl[buf][(c2 * 4 + hh * 2 + 0) * 512 + lane * 8];
                    const bf16x8 vf1 = *(const bf16x8*)&Vl[buf][(c2 * 4 + hh * 2 + 1) * 512 + lane * 8];
                    oA[c2] = __builtin_amdgcn_mfma_f32_16x16x32_bf16(pfA0, vf0, oA[c2], 0, 0, 0);
                    oA[c2] = __builtin_amdgcn_mfma_f32_16x16x32_bf16(pfA1, vf1, oA[c2], 0, 0, 0);
                    oB[c2] = __builtin_amdgcn_mfma_f32_16x16x32_bf16(pfB0, vf0, oB[c2], 0, 0, 0);
                    oB[c2] = __builtin_amdgcn_mfma_f32_16x16x32_bf16(pfB1, vf1, oB[c2], 0, 0, 0);
                }
            }
            buf ^= 1;
        }

        // reduce l across the 4 quads; rinv per output row
        lsumA += __shfl_xor(lsumA, 16, 64);
        lsumA += __shfl_xor(lsumA, 32, 64);
        lsumB += __shfl_xor(lsumB, 16, 64);
        lsumB += __shfl_xor(lsumB, 32, 64);
        float rinvA[4], rinvB[4];
#pragma unroll
        for (int r = 0; r < 4; r++) {
            rinvA[r] = 1.0f / __shfl(lsumA, qd * 4 + r, 64);
            rinvB[r] = 1.0f / __shfl(lsumB, qd * 4 + r, 64);
        }

        // write Ob in proj-A-tiled layout: group A at m, group B at m+1
        const int m = bh * 128 + (q0 >> 4);          // q0>>4 = tile*8 + 2w
        const int mm = m & 15;                       // (m+1)&15 = mm+1 (mm even)
        u16* Ot = Ob + ((size_t)(m >> 4) * 32) * 512;
#pragma unroll
        for (int c2 = 0; c2 < 4; c2++)
#pragma unroll
            for (int r = 0; r < 4; r++) {
                const int kk5 = (qd * 4 + r) * 2 + (c2 >> 1);
                const int s3 = (c2 * 2 + (la >> 3)) & 3;
                const size_t base = (size_t)kk5 * 512 + 16 * s3 * 8 + (la & 7);
                Ot[base + mm * 8]       = f2bf(oA[c2][r] * rinvA[r]);
                Ot[base + (mm + 1) * 8] = f2bf(oB[c2][r] * rinvB[r]);
            }
    }
}

// ---------------- launch -----------------------------------------------------
extern "C" void kernel_launch(void* const* d_in, const int* in_sizes, int n_in,
                              void* d_out, int out_size, void* d_ws, size_t ws_size,
                              hipStream_t stream)
{
    const float* x     = (const float*)d_in[0];
    // d_in[1] = attention_mask: structurally causal tril; enforced analytically.
    const float* wqkv  = (const float*)d_in[2];
    const float* bqkv  = (const float*)d_in[3];
    const float* wproj = (const float*)d_in[4];
    const float* bproj = (const float*)d_in[5];
    float* out = (float*)d_out;

    // workspace layout (u16 units), ~50 MB total
    u16* ws     = (u16*)d_ws;
    u16* xb     = ws;                       // 4096*1024   (tiled)
    u16* wqkvb  = xb + 4096 * 1024;         // 3072*1024   (tiled)
    u16* wprojb = wqkvb + 3072 * 1024;      // 1024*1024   (tiled)
    u16* Qb     = wprojb + 1024 * 1024;     // 32*2048*64  [B,H,N,D] row-major (pre-scaled by SL_F)
    u16* Kb     = Qb + 32 * 2048 * 64;      // 32*256 chunks (row-major interior)
    u16* VTb    = Kb + 32 * 2048 * 64;      // 32*256 chunks (row-major interior)
    u16* Ob     = VTb + 32 * 2048 * 64;     // 8192 chunks (proj-A tiled)

    convert_k<<<dim3(4096), dim3(256), 0, stream>>>(
        x, wqkv, wproj, xb, wqkvb, wprojb);

    // qkv: 128x128 tile, 2-D grid 24x32 (XCD banding + balanced scatter)
    qkv_gemm<<<dim3(24, 32), dim3(256), 0, stream>>>(
        xb, wqkvb, bqkv, Qb, Kb, VTb);

    // attn: 4 waves x 32 q-rows (Q-block 128), 256 blocks (32 bh x 8 pairs)
    attn_k<<<dim3(256), dim3(256), 0, stream>>>(Qb, Kb, VTb, Ob);

    // proj: 128x64 tile, BK=64, 2-D grid 16x32
    proj_gemm<<<dim3(16, 32), dim3(256), 0, stream>>>(
        Ob, wprojb, bproj, out);
}

// Round 14
// 188.569 us; speedup vs baseline: 1.0350x; 1.0350x over previous
//
#include <hip/hip_runtime.h>
#include <hip/hip_bf16.h>
#include <stdint.h>

// Problem constants (B=2, N=2048, C=1024, H=16, D=64)
#define SL_F 0.18033688011112043f   // SCALE * log2(e): softmax in exp2 domain

typedef unsigned short u16;
typedef unsigned int u32;
typedef __attribute__((ext_vector_type(8))) short bf16x8;   // 8 bf16 = 4 VGPRs
typedef __attribute__((ext_vector_type(4))) float f32x4;

__device__ __forceinline__ u16 f2bf(float f) {
    union { float f; u32 u; } v; v.f = f;
    return (u16)((v.u + 0x7fffu + ((v.u >> 16) & 1u)) >> 16);  // RNE
}
__device__ __forceinline__ u32 pack2bf(float a, float b) {
    union { __hip_bfloat162 h; u32 u; } p;
    p.h = __float22bfloat162_rn(make_float2(a, b));
    return p.u;
}

// async global->LDS, 16B per lane; LDS dest = wave-uniform base + lane*16.
// Global src is PER-LANE: coalescing needs the 64-address SET contiguous,
// not lane-identity order (r11 verified: permuted-slot chunks).
__device__ __forceinline__ void gl_lds16(const u16* g, u16* l) {
    __builtin_amdgcn_global_load_lds(
        (const __attribute__((address_space(1))) u32*)g,
        (__attribute__((address_space(3))) u32*)l, 16, 0, 0);
}

// ---------------- fp32 -> bf16 TILED conversion of x, w_qkv, w_proj ---------
// Fragment-tiled layout (r9, VERIFIED): chunk(g,kb)=1KB, slot order =
// gl_lds16 deposit. Staging = chunk + lane*16 (8 full 128B lines/instr).
__global__ __launch_bounds__(256) void convert_k(
    const float* __restrict__ x, const float* __restrict__ w1,
    const float* __restrict__ w2,
    u16* __restrict__ xb, u16* __restrict__ w1b, u16* __restrict__ w2b)
{
    const int t = blockIdx.x * 256 + threadIdx.x;   // global slot id
    const int XA = 524288, XW1 = 393216;            // slots: 4096*128, 3072*128
    const float* src; u16* dst; int s;
    if (t < XA)            { src = x;  dst = xb;  s = t; }
    else if (t < XA + XW1) { src = w1; dst = w1b; s = t - XA; }
    else                   { src = w2; dst = w2b; s = t - XA - XW1; }
    const int c = s >> 6;                    // chunk (wave-uniform)
    const int u = s & 63;
    const int l = (u >> 2) + 16 * (u & 3);   // slot within chunk
    const int g = c >> 5, kb = c & 31;
    const int row = g * 16 + (l & 15);
    const int k0 = kb * 32 + (l >> 4) * 8;
    const float4 v0 = *(const float4*)&src[(size_t)row * 1024 + k0];
    const float4 v1 = *(const float4*)&src[(size_t)row * 1024 + k0 + 4];
    uint4 o;
    o.x = pack2bf(v0.x, v0.y); o.y = pack2bf(v0.z, v0.w);
    o.z = pack2bf(v1.x, v1.y); o.w = pack2bf(v1.z, v1.w);
    *(uint4*)&dst[((size_t)c * 64 + l) * 8] = o;
}

// ---------------- QKV GEMM: out[m,n] = sum_k A[m,k]*W[n,k] + bias ------------
// r6 proven body + 24x32 grid + r9 tiled A/B staging + r11 row-major-interior
// K/V^T chunks + r12 pre-scaled Q (all verified; unchanged).
__global__ __launch_bounds__(256) void qkv_gemm(
    const u16* __restrict__ A, const u16* __restrict__ Bw,
    const float* __restrict__ bias,
    u16* __restrict__ Qb, u16* __restrict__ Kb, u16* __restrict__ VTb)
{
    __shared__ __align__(16) u16 Al[2][8 * 512];
    __shared__ __align__(16) u16 Bl[2][8 * 512];
    const int tid = threadIdx.x;
    const int lane = tid & 63;
    const int w = tid >> 6;
    const int la = lane & 15, qd = lane >> 4;
    const int m0 = blockIdx.y * 128;
    const int n0 = blockIdx.x * 128;
    const int wm = (w >> 1) * 64, wn = (w & 1) * 64;

    const u16* Ag0 = A + ((size_t)((m0 >> 4) + 2 * w) * 32) * 512 + lane * 8;
    const u16* Ag1 = Ag0 + 32 * 512;
    const u16* Bg0 = Bw + ((size_t)((n0 >> 4) + 2 * w) * 32) * 512 + lane * 8;
    const u16* Bg1 = Bg0 + 32 * 512;

    auto stage = [&](int k0, int b) {
        const size_t ko = (size_t)(k0 >> 5) * 512;
        gl_lds16(Ag0 + ko, &Al[b][(2 * w) * 512]);
        gl_lds16(Ag1 + ko, &Al[b][(2 * w + 1) * 512]);
        gl_lds16(Bg0 + ko, &Bl[b][(2 * w) * 512]);
        gl_lds16(Bg1 + ko, &Bl[b][(2 * w + 1) * 512]);
    };

    f32x4 acc[4][4] = {};
    int buf = 0;
    stage(0, 0);

    for (int k0 = 0; k0 < 1024; k0 += 32) {
        __syncthreads();                       // drains prev prefetch (vmcnt 0)
        if (k0 + 32 < 1024) stage(k0 + 32, buf ^ 1);

        bf16x8 af[4], bfr[4];
#pragma unroll
        for (int i = 0; i < 4; i++)
            af[i] = *(const bf16x8*)&Al[buf][(((unsigned)wm >> 4) + i) * 512 + lane * 8];
#pragma unroll
        for (int j = 0; j < 4; j++)
            bfr[j] = *(const bf16x8*)&Bl[buf][(((unsigned)wn >> 4) + j) * 512 + lane * 8];
#pragma unroll
        for (int i = 0; i < 4; i++)
#pragma unroll
            for (int j = 0; j < 4; j++)
                acc[i][j] = __builtin_amdgcn_mfma_f32_16x16x32_bf16(
                    af[i], bfr[j], acc[i][j], 0, 0, 0);
        buf ^= 1;
    }

    // Epilogue. C/D: col = lane&15 (-> d), row = qd*4 + reg (-> n).
    const int b_ = m0 >> 11;                         // batch (block-uniform)
    const int nb = (m0 & 2047) + wm;                 // token base (64-aligned)
#pragma unroll
    for (int j = 0; j < 4; j++) {
        const int colb = n0 + wn + j * 16;           // wave-uniform
        const int col = colb + la;
        const float bv = bias[col];
        const int t = colb >> 10;                    // wave-uniform selector
        const int hd = col & 1023, h = hd >> 6, d = hd & 63;
        const int bh = b_ * 16 + h;
        if (t == 0) {
            u16* QB = Qb + ((size_t)bh * 2048 + nb) * 64 + d;
#pragma unroll
            for (int i = 0; i < 4; i++)
#pragma unroll
                for (int r = 0; r < 4; r++)
                    QB[(i * 16 + qd * 4 + r) * 64] =
                        f2bf((acc[i][j][r] + bv) * SL_F);   // pre-scaled Q
        } else if (t == 1) {
            u16* KB = Kb + (size_t)bh * 131072
                    + (size_t)((nb >> 4) * 2 + (d >> 5)) * 512 + (d & 31);
#pragma unroll
            for (int i = 0; i < 4; i++)
#pragma unroll
                for (int r = 0; r < 4; r++)
                    KB[i * 1024 + (qd * 4 + r) * 32] = f2bf(acc[i][j][r] + bv);
        } else {
            u16* VB = VTb + (size_t)bh * 131072
                    + (size_t)(d >> 4) * 32768 + (d & 15) * 32;
#pragma unroll
            for (int i = 0; i < 4; i++)
#pragma unroll
                for (int r = 0; r < 4; r++)
                    VB[((nb >> 5) + (i >> 1)) * 512 + (i & 1) * 16 + qd * 4 + r]
                        = f2bf(acc[i][j][r] + bv);
        }
    }
}

// ---------------- proj GEMM, BK=64; A and B both from tiled layouts ----------
// (r10/r11, verified; unchanged)
__global__ __launch_bounds__(256) void proj_gemm(
    const u16* __restrict__ A, const u16* __restrict__ Bw,
    const float* __restrict__ bias, float* __restrict__ Out)
{
    __shared__ __align__(16) u16 Al[2][16 * 512];   // 32 KB
    __shared__ __align__(16) u16 Bl[2][8 * 512];    // 16 KB
    const int tid = threadIdx.x;
    const int lane = tid & 63;
    const int w = tid >> 6;
    const int la = lane & 15, qd = lane >> 4;
    const int K = 1024;
    const int m0 = blockIdx.y * 128;
    const int n0 = blockIdx.x * 64;
    const int wm = (w >> 1) * 64, wn = (w & 1) * 32;

    const u16* Ab[4];
#pragma unroll
    for (int t = 0; t < 4; t++) {
        const int ck = 4 * w + t, g = ck >> 1, h = ck & 1;
        Ab[t] = A + (((size_t)(m0 >> 4) + g) * 32 + h) * 512 + lane * 8;
    }
    const u16* Bg = Bw + ((size_t)((n0 >> 4) + w) * 32) * 512 + lane * 8;

    auto stage = [&](int k0, int b) {
#pragma unroll
        for (int t = 0; t < 4; t++)
            gl_lds16(Ab[t] + (size_t)(k0 >> 5) * 512, &Al[b][(4 * w + t) * 512]);
#pragma unroll
        for (int t = 0; t < 2; t++)
            gl_lds16(Bg + (size_t)((k0 >> 5) + t) * 512, &Bl[b][(2 * w + t) * 512]);
    };

    f32x4 acc[4][2] = {};
    int buf = 0;
    stage(0, 0);

    for (int k0 = 0; k0 < K; k0 += 64) {
        __syncthreads();                       // drains prev prefetch (vmcnt 0)
        if (k0 + 64 < K) stage(k0 + 64, buf ^ 1);

        bf16x8 af[4][2], bfr[2][2];
#pragma unroll
        for (int i = 0; i < 4; i++) {
            const int g = ((unsigned)wm >> 4) + i;
#pragma unroll
            for (int h = 0; h < 2; h++)
                af[i][h] = *(const bf16x8*)&Al[buf][(g * 2 + h) * 512 + lane * 8];
        }
#pragma unroll
        for (int j = 0; j < 2; j++) {
            const int g = ((unsigned)wn >> 4) + j;
#pragma unroll
            for (int h = 0; h < 2; h++)
                bfr[j][h] = *(const bf16x8*)&Bl[buf][(g * 2 + h) * 512 + lane * 8];
        }
#pragma unroll
        for (int i = 0; i < 4; i++)
#pragma unroll
            for (int j = 0; j < 2; j++) {
                f32x4 c = acc[i][j];
                c = __builtin_amdgcn_mfma_f32_16x16x32_bf16(af[i][0], bfr[j][0], c, 0, 0, 0);
                c = __builtin_amdgcn_mfma_f32_16x16x32_bf16(af[i][1], bfr[j][1], c, 0, 0, 0);
                acc[i][j] = c;
            }
        buf ^= 1;
    }

    // Epilogue (fp32 out + bias). C/D layout: col = lane&15, row = qd*4 + r.
#pragma unroll
    for (int j = 0; j < 2; j++) {
        const int col = n0 + wn + j * 16 + la;
        const float bv = bias[col];
#pragma unroll
        for (int i = 0; i < 4; i++)
#pragma unroll
            for (int r = 0; r < 4; r++) {
                const int row = m0 + wm + i * 16 + qd * 4 + r;
                Out[(size_t)row * 1024 + col] = acc[i][j][r] + bv;
            }
    }
}

// ---------------- causal flash attention, Q-block 128, 8 waves, j-step 256 ---
// r14: REVERT r13 (4-wave 32-row variant lost 7us: TLP > LDS-traffic). Base =
// r12 (8 waves x 16 q-rows, best attn 42.2us). r12/r13 established: per-iter
// ~6000 cyc vs ~2500 LDS-port + ~700 VALU -> ~3000 cyc/iter is barrier-convoy
// + dep-chain latency at 1 block/CU. Fix: j-step 256 — stage TWO j128 tiles
// per barrier (K/V dbuf 128KB + P 18KB = 146KB LDS), process as two
// sequential sub-tiles with the identical r12 inner body. Pair {T,15-T} ->
// uniform 9 steps (was 17): ceil((T+1)/2)+ceil((16-T)/2) = 9 for all T.
// Also T5: setprio(1) around MFMA clusters (+4-7% attn, m191).
// Q pre-scaled by SL_F; K/V tiled chunks + permuted-lane staging (r11);
// Ob proj-A-tiled (r10).
__global__ __launch_bounds__(512) void attn_k(
    const u16* __restrict__ Qb, const u16* __restrict__ Kb,
    const u16* __restrict__ VTb, u16* __restrict__ Ob)
{
    __shared__ __align__(16) u16 Kl[2][32 * 512];   // 64 KB: 2 j128-subtiles
    __shared__ __align__(16) u16 Vl[2][32 * 512];   // 64 KB
    __shared__ __align__(16) u16 Pl[8][16 * 72];    // per-wave P, stride 72
    const int bh = blockIdx.x & 31;
    const int pairT = blockIdx.x >> 5;              // 0..7
    const int tid = threadIdx.x;
    const int lane = tid & 63;
    const int w = tid >> 6;                         // 0..7
    const int la = lane & 15, qd = lane >> 4;

    // permuted in-chunk offset: lane l -> row-major interior (l&15)*32 + (l>>4)*8
    const int perm = (lane & 15) * 32 + (lane >> 4) * 8;
    const u16* Kbh = Kb + (size_t)bh * 131072 + perm;
    const u16* Vbh = VTb + (size_t)bh * 131072 + perm;
    u16* Pw = &Pl[w][0];

    // stage a j256 tile starting at j128-index jj (even): 64 chunks, 8/wave.
    // K LDS chunk ck (0..31) <-> global chunk jj*16 + ck (linear).
    // V LDS chunk ck: dg = ck>>3, n32off = ck&7 <-> global dg*64 + jj*4 + n32off.
    auto stage = [&](int jj, int b) {
#pragma unroll
        for (int t = 0; t < 4; t++) {
            const int ck = 4 * w + t;                       // 0..31
            gl_lds16(Kbh + (size_t)(jj * 16 + ck) * 512, &Kl[b][ck * 512]);
            gl_lds16(Vbh + (size_t)((ck >> 3) * 64 + jj * 4 + (ck & 7)) * 512,
                     &Vl[b][ck * 512]);
        }
    };

    int buf = 0;
    stage(0, 0);                                    // prologue for first tile

    for (int half = 0; half < 2; half++) {
        const int tile = (half == 0) ? pairT : 15 - pairT;  // j128-tile count-1
        const int q0 = tile * 128 + w * 16;
        const int qrow = q0 + la;                   // this lane's q-row
        const int S = (tile + 2) >> 1;              // j256 steps for this tile

        const u16* Qp = Qb + ((size_t)bh * 2048 + q0 + la) * 64 + qd * 8;
        const bf16x8 qf0 = *(const bf16x8*)Qp;
        const bf16x8 qf1 = *(const bf16x8*)(Qp + 32);

        f32x4 o[4] = {};
        float lsum = 0.f;

        for (int st = 0; st < S; ++st) {
            const int jj = 2 * st;
            __syncthreads();   // drains prev prefetch (vmcnt 0, all waves)

            const int nj = (st + 1 < S) ? (jj + 2) : ((half == 0) ? 0 : -1);
            if (nj >= 0) stage(nj, buf ^ 1);

#pragma unroll
            for (int sub = 0; sub < 2; ++sub) {
                const int jjj = jj + sub;            // j128 index
                if (jjj > tile) continue;            // wave-uniform guard
                const int koff = sub * 16;           // K chunk base for subtile

                // S^T = K Q'^T (Q pre-scaled): 8 j-subtiles of 16
                f32x4 s[8];
                __builtin_amdgcn_s_setprio(1);
#pragma unroll
                for (int c = 0; c < 8; c++) {
                    f32x4 z = {};
                    const bf16x8 kf0 = *(const bf16x8*)&Kl[buf][(koff + c * 2 + 0) * 512 + lane * 8];
                    const bf16x8 kf1 = *(const bf16x8*)&Kl[buf][(koff + c * 2 + 1) * 512 + lane * 8];
                    z = __builtin_amdgcn_mfma_f32_16x16x32_bf16(kf0, qf0, z, 0, 0, 0);
                    z = __builtin_amdgcn_mfma_f32_16x16x32_bf16(kf1, qf1, z, 0, 0, 0);
                    s[c] = z;
                }
                __builtin_amdgcn_s_setprio(0);

                // p = exp2(s); causal mask only on the diagonal j128 tile
                if (jjj == tile) {
#pragma unroll
                    for (int c = 0; c < 8; c++)
#pragma unroll
                        for (int r = 0; r < 4; r++) {
                            const int j = jjj * 128 + c * 16 + qd * 4 + r;
                            float v = s[c][r];
                            v = (j > qrow) ? -1e30f : v;
                            s[c][r] = __builtin_amdgcn_exp2f(v);
                        }
                } else {
#pragma unroll
                    for (int c = 0; c < 8; c++)
#pragma unroll
                        for (int r = 0; r < 4; r++)
                            s[c][r] = __builtin_amdgcn_exp2f(s[c][r]);
                }
#pragma unroll
                for (int c = 0; c < 8; c++)
#pragma unroll
                    for (int r = 0; r < 4; r++)
                        lsum += s[c][r];

                // PV in two j-64 halves, reusing the per-wave P buffer
                // (same-wave DS is in-order across hh and sub)
#pragma unroll
                for (int hh = 0; hh < 2; hh++) {
#pragma unroll
                    for (int c = 0; c < 4; c++) {
                        uint2 pw;
                        pw.x = pack2bf(s[hh * 4 + c][0], s[hh * 4 + c][1]);
                        pw.y = pack2bf(s[hh * 4 + c][2], s[hh * 4 + c][3]);
                        *(uint2*)&Pw[la * 72 + c * 16 + qd * 4] = pw;
                    }
                    const bf16x8 pf0 = *(const bf16x8*)&Pw[la * 72 + qd * 8];
                    const bf16x8 pf1 = *(const bf16x8*)&Pw[la * 72 + 32 + qd * 8];
                    __builtin_amdgcn_s_setprio(1);
#pragma unroll
                    for (int c2 = 0; c2 < 4; c2++) {
                        const bf16x8 vf0 = *(const bf16x8*)&Vl[buf][(c2 * 8 + sub * 4 + hh * 2 + 0) * 512 + lane * 8];
                        const bf16x8 vf1 = *(const bf16x8*)&Vl[buf][(c2 * 8 + sub * 4 + hh * 2 + 1) * 512 + lane * 8];
                        o[c2] = __builtin_amdgcn_mfma_f32_16x16x32_bf16(pf0, vf0, o[c2], 0, 0, 0);
                        o[c2] = __builtin_amdgcn_mfma_f32_16x16x32_bf16(pf1, vf1, o[c2], 0, 0, 0);
                    }
                    __builtin_amdgcn_s_setprio(0);
                }
            }
            buf ^= 1;
        }

        // reduce l across the 4 quads (lane la holds row la's partials)
        lsum += __shfl_xor(lsum, 16, 64);
        lsum += __shfl_xor(lsum, 32, 64);
        float rinv[4];
#pragma unroll
        for (int r = 0; r < 4; r++)
            rinv[r] = 1.0f / __shfl(lsum, qd * 4 + r, 64);

        // write Ob in proj-A-tiled layout: m = bh*128 + tile*8 + w (uniform),
        // k = (qd*4+r)*64 + c2*16 + la
        const int m = bh * 128 + (q0 >> 4);
        u16* Ot = Ob + ((size_t)(m >> 4) * 32) * 512;
        const int mm = m & 15;
#pragma unroll
        for (int c2 = 0; c2 < 4; c2++)
#pragma unroll
            for (int r = 0; r < 4; r++) {
                const int kk5 = (qd * 4 + r) * 2 + (c2 >> 1);
                const int s3 = (c2 * 2 + (la >> 3)) & 3;
                Ot[(size_t)kk5 * 512 + (mm + 16 * s3) * 8 + (la & 7)] =
                    f2bf(o[c2][r] * rinv[r]);
            }
    }
}

// ---------------- launch -----------------------------------------------------
extern "C" void kernel_launch(void* const* d_in, const int* in_sizes, int n_in,
                              void* d_out, int out_size, void* d_ws, size_t ws_size,
                              hipStream_t stream)
{
    const float* x     = (const float*)d_in[0];
    // d_in[1] = attention_mask: structurally causal tril; enforced analytically.
    const float* wqkv  = (const float*)d_in[2];
    const float* bqkv  = (const float*)d_in[3];
    const float* wproj = (const float*)d_in[4];
    const float* bproj = (const float*)d_in[5];
    float* out = (float*)d_out;

    // workspace layout (u16 units), ~50 MB total
    u16* ws     = (u16*)d_ws;
    u16* xb     = ws;                       // 4096*1024   (tiled)
    u16* wqkvb  = xb + 4096 * 1024;         // 3072*1024   (tiled)
    u16* wprojb = wqkvb + 3072 * 1024;      // 1024*1024   (tiled)
    u16* Qb     = wprojb + 1024 * 1024;     // 32*2048*64  [B,H,N,D] row-major (pre-scaled by SL_F)
    u16* Kb     = Qb + 32 * 2048 * 64;      // 32*256 chunks (row-major interior)
    u16* VTb    = Kb + 32 * 2048 * 64;      // 32*256 chunks (row-major interior)
    u16* Ob     = VTb + 32 * 2048 * 64;     // 8192 chunks (proj-A tiled)

    convert_k<<<dim3(4096), dim3(256), 0, stream>>>(
        x, wqkv, wproj, xb, wqkvb, wprojb);

    // qkv: 128x128 tile, 2-D grid 24x32 (XCD banding + balanced scatter)
    qkv_gemm<<<dim3(24, 32), dim3(256), 0, stream>>>(
        xb, wqkvb, bqkv, Qb, Kb, VTb);

    // attn: Q-block 128, 8 waves, j-step 256, 256 blocks (32 bh x 8 pairs)
    attn_k<<<dim3(256), dim3(512), 0, stream>>>(Qb, Kb, VTb, Ob);

    // proj: 128x64 tile, BK=64, 2-D grid 16x32
    proj_gemm<<<dim3(16, 32), dim3(256), 0, stream>>>(
        Ob, wprojb, bproj, out);
}

// Round 15
// 187.356 us; speedup vs baseline: 1.0417x; 1.0065x over previous
//
#include <hip/hip_runtime.h>
#include <hip/hip_bf16.h>
#include <stdint.h>

// Problem constants (B=2, N=2048, C=1024, H=16, D=64)
#define SL_F 0.18033688011112043f   // SCALE * log2(e): softmax in exp2 domain

typedef unsigned short u16;
typedef unsigned int u32;
typedef __attribute__((ext_vector_type(8))) short bf16x8;   // 8 bf16 = 4 VGPRs
typedef __attribute__((ext_vector_type(4))) float f32x4;

__device__ __forceinline__ u16 f2bf(float f) {
    union { float f; u32 u; } v; v.f = f;
    return (u16)((v.u + 0x7fffu + ((v.u >> 16) & 1u)) >> 16);  // RNE
}
__device__ __forceinline__ u32 pack2bf(float a, float b) {
    union { __hip_bfloat162 h; u32 u; } p;
    p.h = __float22bfloat162_rn(make_float2(a, b));
    return p.u;
}

// async global->LDS, 16B per lane; LDS dest = wave-uniform base + lane*16.
// Global src is PER-LANE: coalescing needs the 64-address SET contiguous,
// not lane-identity order (r11 verified: permuted-slot chunks).
__device__ __forceinline__ void gl_lds16(const u16* g, u16* l) {
    __builtin_amdgcn_global_load_lds(
        (const __attribute__((address_space(1))) u32*)g,
        (__attribute__((address_space(3))) u32*)l, 16, 0, 0);
}

// ---------------- fp32 -> bf16 TILED conversion of x, w_qkv, w_proj ---------
// Fragment-tiled layout (r9, VERIFIED): chunk(g,kb)=1KB, slot order =
// gl_lds16 deposit. Staging = chunk + lane*16 (8 full 128B lines/instr).
__global__ __launch_bounds__(256) void convert_k(
    const float* __restrict__ x, const float* __restrict__ w1,
    const float* __restrict__ w2,
    u16* __restrict__ xb, u16* __restrict__ w1b, u16* __restrict__ w2b)
{
    const int t = blockIdx.x * 256 + threadIdx.x;   // global slot id
    const int XA = 524288, XW1 = 393216;            // slots: 4096*128, 3072*128
    const float* src; u16* dst; int s;
    if (t < XA)            { src = x;  dst = xb;  s = t; }
    else if (t < XA + XW1) { src = w1; dst = w1b; s = t - XA; }
    else                   { src = w2; dst = w2b; s = t - XA - XW1; }
    const int c = s >> 6;                    // chunk (wave-uniform)
    const int u = s & 63;
    const int l = (u >> 2) + 16 * (u & 3);   // slot within chunk
    const int g = c >> 5, kb = c & 31;
    const int row = g * 16 + (l & 15);
    const int k0 = kb * 32 + (l >> 4) * 8;
    const float4 v0 = *(const float4*)&src[(size_t)row * 1024 + k0];
    const float4 v1 = *(const float4*)&src[(size_t)row * 1024 + k0 + 4];
    uint4 o;
    o.x = pack2bf(v0.x, v0.y); o.y = pack2bf(v0.z, v0.w);
    o.z = pack2bf(v1.x, v1.y); o.w = pack2bf(v1.z, v1.w);
    *(uint4*)&dst[((size_t)c * 64 + l) * 8] = o;
}

// ---------------- QKV GEMM: out[m,n] = sum_k A[m,k]*W[n,k] + bias ------------
// r6 proven body + 24x32 grid + r9 tiled A/B staging + r11 row-major-interior
// K/V^T chunks + r12 pre-scaled Q (all verified; unchanged).
__global__ __launch_bounds__(256) void qkv_gemm(
    const u16* __restrict__ A, const u16* __restrict__ Bw,
    const float* __restrict__ bias,
    u16* __restrict__ Qb, u16* __restrict__ Kb, u16* __restrict__ VTb)
{
    __shared__ __align__(16) u16 Al[2][8 * 512];
    __shared__ __align__(16) u16 Bl[2][8 * 512];
    const int tid = threadIdx.x;
    const int lane = tid & 63;
    const int w = tid >> 6;
    const int la = lane & 15, qd = lane >> 4;
    const int m0 = blockIdx.y * 128;
    const int n0 = blockIdx.x * 128;
    const int wm = (w >> 1) * 64, wn = (w & 1) * 64;

    const u16* Ag0 = A + ((size_t)((m0 >> 4) + 2 * w) * 32) * 512 + lane * 8;
    const u16* Ag1 = Ag0 + 32 * 512;
    const u16* Bg0 = Bw + ((size_t)((n0 >> 4) + 2 * w) * 32) * 512 + lane * 8;
    const u16* Bg1 = Bg0 + 32 * 512;

    auto stage = [&](int k0, int b) {
        const size_t ko = (size_t)(k0 >> 5) * 512;
        gl_lds16(Ag0 + ko, &Al[b][(2 * w) * 512]);
        gl_lds16(Ag1 + ko, &Al[b][(2 * w + 1) * 512]);
        gl_lds16(Bg0 + ko, &Bl[b][(2 * w) * 512]);
        gl_lds16(Bg1 + ko, &Bl[b][(2 * w + 1) * 512]);
    };

    f32x4 acc[4][4] = {};
    int buf = 0;
    stage(0, 0);

    for (int k0 = 0; k0 < 1024; k0 += 32) {
        __syncthreads();                       // drains prev prefetch (vmcnt 0)
        if (k0 + 32 < 1024) stage(k0 + 32, buf ^ 1);

        bf16x8 af[4], bfr[4];
#pragma unroll
        for (int i = 0; i < 4; i++)
            af[i] = *(const bf16x8*)&Al[buf][(((unsigned)wm >> 4) + i) * 512 + lane * 8];
#pragma unroll
        for (int j = 0; j < 4; j++)
            bfr[j] = *(const bf16x8*)&Bl[buf][(((unsigned)wn >> 4) + j) * 512 + lane * 8];
#pragma unroll
        for (int i = 0; i < 4; i++)
#pragma unroll
            for (int j = 0; j < 4; j++)
                acc[i][j] = __builtin_amdgcn_mfma_f32_16x16x32_bf16(
                    af[i], bfr[j], acc[i][j], 0, 0, 0);
        buf ^= 1;
    }

    // Epilogue. C/D: col = lane&15 (-> d), row = qd*4 + reg (-> n).
    const int b_ = m0 >> 11;                         // batch (block-uniform)
    const int nb = (m0 & 2047) + wm;                 // token base (64-aligned)
#pragma unroll
    for (int j = 0; j < 4; j++) {
        const int colb = n0 + wn + j * 16;           // wave-uniform
        const int col = colb + la;
        const float bv = bias[col];
        const int t = colb >> 10;                    // wave-uniform selector
        const int hd = col & 1023, h = hd >> 6, d = hd & 63;
        const int bh = b_ * 16 + h;
        if (t == 0) {
            u16* QB = Qb + ((size_t)bh * 2048 + nb) * 64 + d;
#pragma unroll
            for (int i = 0; i < 4; i++)
#pragma unroll
                for (int r = 0; r < 4; r++)
                    QB[(i * 16 + qd * 4 + r) * 64] =
                        f2bf((acc[i][j][r] + bv) * SL_F);   // pre-scaled Q
        } else if (t == 1) {
            u16* KB = Kb + (size_t)bh * 131072
                    + (size_t)((nb >> 4) * 2 + (d >> 5)) * 512 + (d & 31);
#pragma unroll
            for (int i = 0; i < 4; i++)
#pragma unroll
                for (int r = 0; r < 4; r++)
                    KB[i * 1024 + (qd * 4 + r) * 32] = f2bf(acc[i][j][r] + bv);
        } else {
            u16* VB = VTb + (size_t)bh * 131072
                    + (size_t)(d >> 4) * 32768 + (d & 15) * 32;
#pragma unroll
            for (int i = 0; i < 4; i++)
#pragma unroll
                for (int r = 0; r < 4; r++)
                    VB[((nb >> 5) + (i >> 1)) * 512 + (i & 1) * 16 + qd * 4 + r]
                        = f2bf(acc[i][j][r] + bv);
        }
    }
}

// ---------------- proj GEMM, BK=64; A and B both from tiled layouts ----------
// (r10/r11, verified; unchanged)
__global__ __launch_bounds__(256) void proj_gemm(
    const u16* __restrict__ A, const u16* __restrict__ Bw,
    const float* __restrict__ bias, float* __restrict__ Out)
{
    __shared__ __align__(16) u16 Al[2][16 * 512];   // 32 KB
    __shared__ __align__(16) u16 Bl[2][8 * 512];    // 16 KB
    const int tid = threadIdx.x;
    const int lane = tid & 63;
    const int w = tid >> 6;
    const int la = lane & 15, qd = lane >> 4;
    const int K = 1024;
    const int m0 = blockIdx.y * 128;
    const int n0 = blockIdx.x * 64;
    const int wm = (w >> 1) * 64, wn = (w & 1) * 32;

    const u16* Ab[4];
#pragma unroll
    for (int t = 0; t < 4; t++) {
        const int ck = 4 * w + t, g = ck >> 1, h = ck & 1;
        Ab[t] = A + (((size_t)(m0 >> 4) + g) * 32 + h) * 512 + lane * 8;
    }
    const u16* Bg = Bw + ((size_t)((n0 >> 4) + w) * 32) * 512 + lane * 8;

    auto stage = [&](int k0, int b) {
#pragma unroll
        for (int t = 0; t < 4; t++)
            gl_lds16(Ab[t] + (size_t)(k0 >> 5) * 512, &Al[b][(4 * w + t) * 512]);
#pragma unroll
        for (int t = 0; t < 2; t++)
            gl_lds16(Bg + (size_t)((k0 >> 5) + t) * 512, &Bl[b][(2 * w + t) * 512]);
    };

    f32x4 acc[4][2] = {};
    int buf = 0;
    stage(0, 0);

    for (int k0 = 0; k0 < K; k0 += 64) {
        __syncthreads();                       // drains prev prefetch (vmcnt 0)
        if (k0 + 64 < K) stage(k0 + 64, buf ^ 1);

        bf16x8 af[4][2], bfr[2][2];
#pragma unroll
        for (int i = 0; i < 4; i++) {
            const int g = ((unsigned)wm >> 4) + i;
#pragma unroll
            for (int h = 0; h < 2; h++)
                af[i][h] = *(const bf16x8*)&Al[buf][(g * 2 + h) * 512 + lane * 8];
        }
#pragma unroll
        for (int j = 0; j < 2; j++) {
            const int g = ((unsigned)wn >> 4) + j;
#pragma unroll
            for (int h = 0; h < 2; h++)
                bfr[j][h] = *(const bf16x8*)&Bl[buf][(g * 2 + h) * 512 + lane * 8];
        }
#pragma unroll
        for (int i = 0; i < 4; i++)
#pragma unroll
            for (int j = 0; j < 2; j++) {
                f32x4 c = acc[i][j];
                c = __builtin_amdgcn_mfma_f32_16x16x32_bf16(af[i][0], bfr[j][0], c, 0, 0, 0);
                c = __builtin_amdgcn_mfma_f32_16x16x32_bf16(af[i][1], bfr[j][1], c, 0, 0, 0);
                acc[i][j] = c;
            }
        buf ^= 1;
    }

    // Epilogue (fp32 out + bias). C/D layout: col = lane&15, row = qd*4 + r.
#pragma unroll
    for (int j = 0; j < 2; j++) {
        const int col = n0 + wn + j * 16 + la;
        const float bv = bias[col];
#pragma unroll
        for (int i = 0; i < 4; i++)
#pragma unroll
            for (int r = 0; r < 4; r++) {
                const int row = m0 + wm + i * 16 + qd * 4 + r;
                Out[(size_t)row * 1024 + col] = acc[i][j][r] + bv;
            }
    }
}

// ---------------- causal flash attention, j-step 64, 2 blocks/CU -------------
// r15: TLP is the starved resource (r13: halving waves -7us; r11 vs r12:
// block org neutral at fixed 8 waves/CU; r12/r14: byte/barrier cuts ~nil).
// j-step 64 shrinks LDS to 50KB (K 2x8 + V 2x8 + P 18) -> 2 blocks/CU =
// 16 waves/CU (was 8). Grid 512 = 32 bh (low bits, XCD affinity: 4 heads/XCD
// = 1MB K/V in L2) x 16 tile-slots s; T = s<8 ? s : 23-s so co-resident
// blocks (c, c+256) sum to a uniform 34 iters. Inner body = r12 halved
// (s[4], 4+4 MFMA, same P round-trip, same permuted-lane staging). Waves 0-3
// skip the fully-masked last j64 tile (wave-uniform; barrier kept).
// Q pre-scaled by SL_F; K/V row-major-interior chunks (r11); Ob proj-A-tiled.
__global__ __launch_bounds__(512, 4) void attn_k(
    const u16* __restrict__ Qb, const u16* __restrict__ Kb,
    const u16* __restrict__ VTb, u16* __restrict__ Ob)
{
    __shared__ __align__(16) u16 Kl[2][8 * 512];    // 16 KB: j64 x d64
    __shared__ __align__(16) u16 Vl[2][8 * 512];    // 16 KB
    __shared__ __align__(16) u16 Pl[8][16 * 72];    // per-wave P, stride 72
    const int bh = blockIdx.x & 31;
    const int s = (blockIdx.x >> 5) & 15;           // tile slot
    const int T = (s < 8) ? s : 23 - s;             // q-tile index 0..15
    const int tid = threadIdx.x;
    const int lane = tid & 63;
    const int w = tid >> 6;                         // 0..7
    const int la = lane & 15, qd = lane >> 4;

    // permuted in-chunk offset: lane l -> row-major interior (l&15)*32 + (l>>4)*8
    const int perm = (lane & 15) * 32 + (lane >> 4) * 8;
    const u16* Kbh = Kb + (size_t)bh * 131072 + perm;
    const u16* Vbh = VTb + (size_t)bh * 131072 + perm;
    u16* Pw = &Pl[w][0];

    // stage j64 tile jt: 16 chunks (K 8 + V 8), 2 per wave.
    // K global chunk = jt*8 + ck (ck = n16grp*2 + d32half, linear).
    // V global chunk = dg*64 + jt*2 + u  (LDS ck-8 = dg*2 + u).
    auto stage = [&](int jt, int b) {
#pragma unroll
        for (int t = 0; t < 2; t++) {
            const int ck = 2 * w + t;               // 0..15
            if (ck < 8) {
                gl_lds16(Kbh + (size_t)(jt * 8 + ck) * 512, &Kl[b][ck * 512]);
            } else {
                const int cv = ck - 8;              // dg*2 + u
                gl_lds16(Vbh + (size_t)((cv >> 1) * 64 + jt * 2 + (cv & 1)) * 512,
                         &Vl[b][cv * 512]);
            }
        }
    };

    const int q0 = T * 128 + w * 16;
    const int qrow = q0 + la;
    const int JT = 2 * T + 2;                       // j64 iters

    const u16* Qp = Qb + ((size_t)bh * 2048 + q0 + la) * 64 + qd * 8;
    const bf16x8 qf0 = *(const bf16x8*)Qp;
    const bf16x8 qf1 = *(const bf16x8*)(Qp + 32);

    f32x4 o[4] = {};
    float lsum = 0.f;

    int buf = 0;
    stage(0, 0);

    for (int jt = 0; jt < JT; ++jt) {
        __syncthreads();   // drains prev prefetch (vmcnt 0, all waves)
        if (jt + 1 < JT) stage(jt + 1, buf ^ 1);

        // wave-uniform skip: last tile fully masked for waves 0-3
        if (jt * 64 <= q0 + 15) {
            // S^T = K Q'^T (Q pre-scaled): 4 j16-subtiles
            f32x4 sv[4];
            __builtin_amdgcn_s_setprio(1);
#pragma unroll
            for (int c = 0; c < 4; c++) {
                f32x4 z = {};
                const bf16x8 kf0 = *(const bf16x8*)&Kl[buf][(c * 2 + 0) * 512 + lane * 8];
                const bf16x8 kf1 = *(const bf16x8*)&Kl[buf][(c * 2 + 1) * 512 + lane * 8];
                z = __builtin_amdgcn_mfma_f32_16x16x32_bf16(kf0, qf0, z, 0, 0, 0);
                z = __builtin_amdgcn_mfma_f32_16x16x32_bf16(kf1, qf1, z, 0, 0, 0);
                sv[c] = z;
            }
            __builtin_amdgcn_s_setprio(0);

            // p = exp2(s); mask only when this j64 tile can cross the diagonal
            if (jt * 64 + 63 > q0) {
#pragma unroll
                for (int c = 0; c < 4; c++)
#pragma unroll
                    for (int r = 0; r < 4; r++) {
                        const int j = jt * 64 + c * 16 + qd * 4 + r;
                        float v = sv[c][r];
                        v = (j > qrow) ? -1e30f : v;
                        sv[c][r] = __builtin_amdgcn_exp2f(v);
                    }
            } else {
#pragma unroll
                for (int c = 0; c < 4; c++)
#pragma unroll
                    for (int r = 0; r < 4; r++)
                        sv[c][r] = __builtin_amdgcn_exp2f(sv[c][r]);
            }
#pragma unroll
            for (int c = 0; c < 4; c++)
#pragma unroll
                for (int r = 0; r < 4; r++)
                    lsum += sv[c][r];

            // P round-trip (row la = q, col = j in 0..63), then PV in two
            // j32 halves (same-wave DS is in-order)
#pragma unroll
            for (int c = 0; c < 4; c++) {
                uint2 pw;
                pw.x = pack2bf(sv[c][0], sv[c][1]);
                pw.y = pack2bf(sv[c][2], sv[c][3]);
                *(uint2*)&Pw[la * 72 + c * 16 + qd * 4] = pw;
            }
#pragma unroll
            for (int hh = 0; hh < 2; hh++) {
                const bf16x8 pf = *(const bf16x8*)&Pw[la * 72 + hh * 32 + qd * 8];
                __builtin_amdgcn_s_setprio(1);
#pragma unroll
                for (int c2 = 0; c2 < 4; c2++) {
                    const bf16x8 vf = *(const bf16x8*)&Vl[buf][(c2 * 2 + hh) * 512 + lane * 8];
                    o[c2] = __builtin_amdgcn_mfma_f32_16x16x32_bf16(pf, vf, o[c2], 0, 0, 0);
                }
                __builtin_amdgcn_s_setprio(0);
            }
        }
        buf ^= 1;
    }

    // reduce l across the 4 quads (lane la holds row la's partials)
    lsum += __shfl_xor(lsum, 16, 64);
    lsum += __shfl_xor(lsum, 32, 64);
    float rinv[4];
#pragma unroll
    for (int r = 0; r < 4; r++)
        rinv[r] = 1.0f / __shfl(lsum, qd * 4 + r, 64);

    // write Ob in proj-A-tiled layout: m = bh*128 + T*8 + w (wave-uniform),
    // k = (qd*4+r)*64 + c2*16 + la
    const int m = bh * 128 + (q0 >> 4);
    u16* Ot = Ob + ((size_t)(m >> 4) * 32) * 512;
    const int mm = m & 15;
#pragma unroll
    for (int c2 = 0; c2 < 4; c2++)
#pragma unroll
        for (int r = 0; r < 4; r++) {
            const int kk5 = (qd * 4 + r) * 2 + (c2 >> 1);
            const int s3 = (c2 * 2 + (la >> 3)) & 3;
            Ot[(size_t)kk5 * 512 + (mm + 16 * s3) * 8 + (la & 7)] =
                f2bf(o[c2][r] * rinv[r]);
        }
}

// ---------------- launch -----------------------------------------------------
extern "C" void kernel_launch(void* const* d_in, const int* in_sizes, int n_in,
                              void* d_out, int out_size, void* d_ws, size_t ws_size,
                              hipStream_t stream)
{
    const float* x     = (const float*)d_in[0];
    // d_in[1] = attention_mask: structurally causal tril; enforced analytically.
    const float* wqkv  = (const float*)d_in[2];
    const float* bqkv  = (const float*)d_in[3];
    const float* wproj = (const float*)d_in[4];
    const float* bproj = (const float*)d_in[5];
    float* out = (float*)d_out;

    // workspace layout (u16 units), ~50 MB total
    u16* ws     = (u16*)d_ws;
    u16* xb     = ws;                       // 4096*1024   (tiled)
    u16* wqkvb  = xb + 4096 * 1024;         // 3072*1024   (tiled)
    u16* wprojb = wqkvb + 3072 * 1024;      // 1024*1024   (tiled)
    u16* Qb     = wprojb + 1024 * 1024;     // 32*2048*64  [B,H,N,D] row-major (pre-scaled by SL_F)
    u16* Kb     = Qb + 32 * 2048 * 64;      // 32*256 chunks (row-major interior)
    u16* VTb    = Kb + 32 * 2048 * 64;      // 32*256 chunks (row-major interior)
    u16* Ob     = VTb + 32 * 2048 * 64;     // 8192 chunks (proj-A tiled)

    convert_k<<<dim3(4096), dim3(256), 0, stream>>>(
        x, wqkv, wproj, xb, wqkvb, wprojb);

    // qkv: 128x128 tile, 2-D grid 24x32 (XCD banding + balanced scatter)
    qkv_gemm<<<dim3(24, 32), dim3(256), 0, stream>>>(
        xb, wqkvb, bqkv, Qb, Kb, VTb);

    // attn: j-step 64, 512 blocks (32 bh x 16 slots) x 8 waves = 2 blocks/CU
    attn_k<<<dim3(512), dim3(512), 0, stream>>>(Qb, Kb, VTb, Ob);

    // proj: 128x64 tile, BK=64, 2-D grid 16x32
    proj_gemm<<<dim3(16, 32), dim3(256), 0, stream>>>(
        Ob, wprojb, bproj, out);
}